// Round 1
// baseline (562.565 us; speedup 1.0000x reference)
//
#include <hip/hip_runtime.h>

#define HDIM 128
#define VOCAB 800
#define FB 16

// ---------- fold W_f into W_s bottom half: Wfs = W_f @ W_s[128:], bfs = b_f @ W_s[128:] + b_s
__global__ void k_prep_w(const float* __restrict__ W_f, const float* __restrict__ b_f,
                         const float* __restrict__ W_s, const float* __restrict__ b_s,
                         float* __restrict__ Wfs, float* __restrict__ bfs) {
    int j = threadIdx.x;
    int i = blockIdx.x;
    if (i < HDIM) {
        float acc = 0.f;
        for (int k = 0; k < HDIM; ++k)
            acc = fmaf(W_f[i * HDIM + k], W_s[(HDIM + k) * HDIM + j], acc);
        Wfs[i * HDIM + j] = acc;
    } else {
        float acc = b_s[j];
        for (int k = 0; k < HDIM; ++k)
            acc = fmaf(b_f[k], W_s[(HDIM + k) * HDIM + j], acc);
        bfs[j] = acc;
    }
}

// ---------- E2 = emb_table @ Wfs   [VOCAB,128]
__global__ void k_E2(const float* __restrict__ emb, const float* __restrict__ Wfs,
                     float* __restrict__ E2) {
    int j = threadIdx.x, v = blockIdx.x;
    float acc = 0.f;
    for (int k = 0; k < HDIM; ++k)
        acc = fmaf(emb[v * HDIM + k], Wfs[k * HDIM + j], acc);
    E2[v * HDIM + j] = acc;
}

// ---------- frag_id = argmax(fragments, axis=1), first occurrence
__global__ void k_argmax(const float* __restrict__ frags, int* __restrict__ frag_id, int F) {
    int wave = (int)((blockIdx.x * (long long)blockDim.x + threadIdx.x) >> 6);
    int lane = threadIdx.x & 63;
    if (wave >= F) return;
    const float* r = frags + (size_t)wave * VOCAB;
    float best = -1e30f;
    int bidx = 0;
    for (int i = lane; i < VOCAB; i += 64) {
        float v = r[i];
        if (v > best) { best = v; bidx = i; }   // per-lane indices increase -> keeps first
    }
    for (int off = 32; off > 0; off >>= 1) {
        float ov = __shfl_xor(best, off, 64);
        int   oi = __shfl_xor(bidx, off, 64);
        if (ov > best || (ov == best && oi < bidx)) { best = ov; bidx = oi; }
    }
    if (lane == 0) frag_id[wave] = bidx;
}

// ---------- scatter pass 1: sub[col] += x[row]; counts for both row and col
__global__ void k_scatter1(const float* __restrict__ x, const int* __restrict__ row,
                           const int* __restrict__ col, float* __restrict__ sub,
                           float* __restrict__ cnt_col, float* __restrict__ cnt_row, int E) {
    long long tid = (long long)blockIdx.x * blockDim.x + threadIdx.x;
    int e = (int)(tid >> 7);
    if (e >= E) return;
    int h = (int)(tid & 127);
    int r = row[e], c = col[e];
    atomicAdd(&sub[(size_t)c * HDIM + h], x[(size_t)r * HDIM + h]);
    if (h == 0) {
        atomicAdd(&cnt_col[c], 1.0f);
        atomicAdd(&cnt_row[r], 1.0f);
    }
}

// ---------- femb (in place over sub): femb = (sub/cnt) @ W_s_top + E2[frag_id] + bfs
__global__ void k_femb(float* __restrict__ sub, const float* __restrict__ cnt_col,
                       const int* __restrict__ frag_id, const float* __restrict__ W_s,
                       const float* __restrict__ E2, const float* __restrict__ bfs) {
    __shared__ float s[FB][HDIM];
    int t = threadIdx.x;
    int fbase = blockIdx.x * FB;
    for (int f = 0; f < FB; ++f) {
        float inv = 1.0f / fmaxf(cnt_col[fbase + f], 1.0f);
        s[f][t] = sub[(size_t)(fbase + f) * HDIM + t] * inv;
    }
    __syncthreads();
    float acc[FB];
    float bv = bfs[t];
    for (int f = 0; f < FB; ++f)
        acc[f] = E2[(size_t)frag_id[fbase + f] * HDIM + t] + bv;
    for (int k = 0; k < HDIM; k += 4) {
        float w0 = W_s[(k + 0) * HDIM + t];
        float w1 = W_s[(k + 1) * HDIM + t];
        float w2 = W_s[(k + 2) * HDIM + t];
        float w3 = W_s[(k + 3) * HDIM + t];
#pragma unroll
        for (int f = 0; f < FB; ++f) {
            float4 sv = *reinterpret_cast<const float4*>(&s[f][k]);
            acc[f] = fmaf(sv.x, w0, acc[f]);
            acc[f] = fmaf(sv.y, w1, acc[f]);
            acc[f] = fmaf(sv.z, w2, acc[f]);
            acc[f] = fmaf(sv.w, w3, acc[f]);
        }
    }
    for (int f = 0; f < FB; ++f)
        sub[(size_t)(fbase + f) * HDIM + t] = acc[f];
}

// ---------- scatter pass 2: out[row] += femb[col]
__global__ void k_scatter2(const float* __restrict__ femb, const int* __restrict__ row,
                           const int* __restrict__ col, float* __restrict__ out, int E) {
    long long tid = (long long)blockIdx.x * blockDim.x + threadIdx.x;
    int e = (int)(tid >> 7);
    if (e >= E) return;
    int h = (int)(tid & 127);
    atomicAdd(&out[(size_t)row[e] * HDIM + h], femb[(size_t)col[e] * HDIM + h]);
}

// ---------- out /= max(cnt_row, 1)   (float4 vectorized)
__global__ void k_div(float* __restrict__ out, const float* __restrict__ cnt_row, int N) {
    int tid = blockIdx.x * blockDim.x + threadIdx.x;  // over N*32
    if (tid >= N * 32) return;
    int n = tid >> 5;
    float inv = 1.0f / fmaxf(cnt_row[n], 1.0f);
    float4* p = reinterpret_cast<float4*>(out) + tid;
    float4 v = *p;
    v.x *= inv; v.y *= inv; v.z *= inv; v.w *= inv;
    *p = v;
}

extern "C" void kernel_launch(void* const* d_in, const int* in_sizes, int n_in,
                              void* d_out, int out_size, void* d_ws, size_t ws_size,
                              hipStream_t stream) {
    const float* x         = (const float*)d_in[0];
    const float* fragments = (const float*)d_in[1];
    const float* emb_table = (const float*)d_in[2];
    const float* W_f       = (const float*)d_in[3];
    const float* b_f       = (const float*)d_in[4];
    const float* W_s       = (const float*)d_in[5];
    const float* b_s       = (const float*)d_in[6];
    const int*   row       = (const int*)d_in[7];
    const int*   col       = (const int*)d_in[8];
    float* out = (float*)d_out;

    const int N = 200000, F = 50000, E = 400000;

    float* ws      = (float*)d_ws;
    float* sub     = ws;                        // F*128 floats (reused as femb in-place)
    float* cnt_col = sub + (size_t)F * HDIM;    // F
    float* cnt_row = cnt_col + F;               // N
    int*   frag_id = (int*)(cnt_row + N);       // F
    float* Wfs     = (float*)(frag_id + F);     // 128*128
    float* E2      = Wfs + HDIM * HDIM;         // VOCAB*128
    float* bfs     = E2 + VOCAB * HDIM;         // 128

    hipMemsetAsync(sub, 0, (size_t)F * HDIM * sizeof(float), stream);
    hipMemsetAsync(cnt_col, 0, (size_t)(F + N) * sizeof(float), stream);
    hipMemsetAsync(out, 0, (size_t)N * HDIM * sizeof(float), stream);

    k_prep_w<<<HDIM + 1, HDIM, 0, stream>>>(W_f, b_f, W_s, b_s, Wfs, bfs);
    k_E2<<<VOCAB, HDIM, 0, stream>>>(emb_table, Wfs, E2);
    k_argmax<<<(F + 3) / 4, 256, 0, stream>>>(fragments, frag_id, F);
    k_scatter1<<<(int)(((long long)E * HDIM) / 256), 256, 0, stream>>>(x, row, col, sub,
                                                                       cnt_col, cnt_row, E);
    k_femb<<<F / FB, HDIM, 0, stream>>>(sub, cnt_col, frag_id, W_s, E2, bfs);
    k_scatter2<<<(int)(((long long)E * HDIM) / 256), 256, 0, stream>>>(sub, row, col, out, E);
    k_div<<<(N * 32) / 256, 256, 0, stream>>>(out, cnt_row, N);
}

// Round 2
// 421.187 us; speedup vs baseline: 1.3357x; 1.3357x over previous
//
#include <hip/hip_runtime.h>

#define HDIM 128
#define VOCAB 800
#define FB 16

// ---------- fold W_f into W_s bottom half: Wfs = W_f @ W_s[128:], bfs = b_f @ W_s[128:] + b_s
__global__ void k_prep_w(const float* __restrict__ W_f, const float* __restrict__ b_f,
                         const float* __restrict__ W_s, const float* __restrict__ b_s,
                         float* __restrict__ Wfs, float* __restrict__ bfs) {
    int j = threadIdx.x;
    int i = blockIdx.x;
    if (i < HDIM) {
        float acc = 0.f;
        for (int k = 0; k < HDIM; ++k)
            acc = fmaf(W_f[i * HDIM + k], W_s[(HDIM + k) * HDIM + j], acc);
        Wfs[i * HDIM + j] = acc;
    } else {
        float acc = b_s[j];
        for (int k = 0; k < HDIM; ++k)
            acc = fmaf(b_f[k], W_s[(HDIM + k) * HDIM + j], acc);
        bfs[j] = acc;
    }
}

// ---------- E2 = emb_table @ Wfs   [VOCAB,128]
__global__ void k_E2(const float* __restrict__ emb, const float* __restrict__ Wfs,
                     float* __restrict__ E2) {
    int j = threadIdx.x, v = blockIdx.x;
    float acc = 0.f;
    for (int k = 0; k < HDIM; ++k)
        acc = fmaf(emb[v * HDIM + k], Wfs[k * HDIM + j], acc);
    E2[v * HDIM + j] = acc;
}

// ---------- frag_id = argmax(fragments, axis=1), first occurrence
__global__ void k_argmax(const float* __restrict__ frags, int* __restrict__ frag_id, int F) {
    int wave = (int)((blockIdx.x * (long long)blockDim.x + threadIdx.x) >> 6);
    int lane = threadIdx.x & 63;
    if (wave >= F) return;
    const float* r = frags + (size_t)wave * VOCAB;
    float best = -1e30f;
    int bidx = 0;
    for (int i = lane; i < VOCAB; i += 64) {
        float v = r[i];
        if (v > best) { best = v; bidx = i; }   // per-lane indices increase -> keeps first
    }
    for (int off = 32; off > 0; off >>= 1) {
        float ov = __shfl_xor(best, off, 64);
        int   oi = __shfl_xor(bidx, off, 64);
        if (ov > best || (ov == best && oi < bidx)) { best = ov; bidx = oi; }
    }
    if (lane == 0) frag_id[wave] = bidx;
}

// ---------- CSR build: counts
__global__ void k_count(const int* __restrict__ row, const int* __restrict__ col,
                        int* __restrict__ cntr, int* __restrict__ cntc, int E) {
    int e = blockIdx.x * 256 + threadIdx.x;
    if (e >= E) return;
    atomicAdd(&cntr[row[e]], 1);
    atomicAdd(&cntc[col[e]], 1);
}

// ---------- per-256-block sums
__global__ void k_blocksum(const int* __restrict__ cnt, int L, int* __restrict__ bsum) {
    __shared__ int s[256];
    int t = threadIdx.x;
    int i = blockIdx.x * 256 + t;
    s[t] = (i < L) ? cnt[i] : 0;
    __syncthreads();
    for (int o = 128; o > 0; o >>= 1) {
        if (t < o) s[t] += s[t + o];
        __syncthreads();
    }
    if (t == 0) bsum[blockIdx.x] = s[0];
}

// ---------- exclusive scan of block sums (nb <= 1024), single block
__global__ void k_scan_bsum(int* __restrict__ bsum, int nb) {
    __shared__ int s[1024];
    int t = threadIdx.x;
    int v = (t < nb) ? bsum[t] : 0;
    s[t] = v;
    __syncthreads();
    for (int o = 1; o < 1024; o <<= 1) {
        int a = (t >= o) ? s[t - o] : 0;
        __syncthreads();
        s[t] += a;
        __syncthreads();
    }
    if (t < nb) bsum[t] = s[t] - v;  // exclusive
}

// ---------- base[i] = bsum[block] + exclusive scan within block
__global__ void k_base(const int* __restrict__ cnt, const int* __restrict__ bsum, int L,
                       int* __restrict__ base) {
    __shared__ int s[256];
    int t = threadIdx.x;
    int i = blockIdx.x * 256 + t;
    int v = (i < L) ? cnt[i] : 0;
    s[t] = v;
    __syncthreads();
    for (int o = 1; o < 256; o <<= 1) {
        int a = (t >= o) ? s[t - o] : 0;
        __syncthreads();
        s[t] += a;
        __syncthreads();
    }
    if (i < L) base[i] = bsum[blockIdx.x] + s[t] - v;
}

// ---------- place edges into both CSRs (payload = the opposite endpoint)
__global__ void k_place(const int* __restrict__ row, const int* __restrict__ col,
                        const int* __restrict__ basec, const int* __restrict__ baser,
                        int* __restrict__ curc, int* __restrict__ curr,
                        int* __restrict__ payc, int* __restrict__ payr, int E) {
    int e = blockIdx.x * 256 + threadIdx.x;
    if (e >= E) return;
    int r = row[e], c = col[e];
    int pc = atomicAdd(&curc[c], 1);
    payc[basec[c] + pc] = r;
    int pr = atomicAdd(&curr[r], 1);
    payr[baser[r] + pr] = c;
}

// ---------- fragment pool + femb fused:
// femb[f] = mean_{e in f}(x[row_e]) @ W_s_top + E2[frag_id[f]] + bfs
__global__ void k_frag(const float* __restrict__ x, const int* __restrict__ basec,
                       const int* __restrict__ cntc, const int* __restrict__ payc,
                       const int* __restrict__ frag_id, const float* __restrict__ W_s,
                       const float* __restrict__ E2, const float* __restrict__ bfs,
                       float* __restrict__ femb) {
    __shared__ float s[FB][HDIM];
    int t = threadIdx.x;
    int fb = blockIdx.x * FB;
    for (int f = 0; f < FB; ++f) {
        int fi = fb + f;
        int st = basec[fi], deg = cntc[fi];
        float acc = 0.f;
        for (int i = 0; i < deg; ++i) {
            int r = payc[st + i];
            acc += x[(size_t)r * HDIM + t];
        }
        s[f][t] = acc * (1.0f / fmaxf((float)deg, 1.0f));
    }
    __syncthreads();
    float acc[FB];
    float bv = bfs[t];
    for (int f = 0; f < FB; ++f)
        acc[f] = E2[(size_t)frag_id[fb + f] * HDIM + t] + bv;
    for (int k = 0; k < HDIM; k += 4) {
        float w0 = W_s[(k + 0) * HDIM + t];
        float w1 = W_s[(k + 1) * HDIM + t];
        float w2 = W_s[(k + 2) * HDIM + t];
        float w3 = W_s[(k + 3) * HDIM + t];
#pragma unroll
        for (int f = 0; f < FB; ++f) {
            float4 sv = *reinterpret_cast<const float4*>(&s[f][k]);
            acc[f] = fmaf(sv.x, w0, acc[f]);
            acc[f] = fmaf(sv.y, w1, acc[f]);
            acc[f] = fmaf(sv.z, w2, acc[f]);
            acc[f] = fmaf(sv.w, w3, acc[f]);
        }
    }
    for (int f = 0; f < FB; ++f)
        femb[(size_t)(fb + f) * HDIM + t] = acc[f];
}

// ---------- node pool + divide fused: out[n] = mean_{e in n}(femb[col_e])
__global__ void k_node(const float* __restrict__ femb, const int* __restrict__ baser,
                       const int* __restrict__ cntr, const int* __restrict__ payr,
                       float* __restrict__ out, int N) {
    int t = threadIdx.x;
    int n = blockIdx.x * 2 + (t >> 7);
    int h = t & 127;
    if (n >= N) return;
    int st = baser[n], deg = cntr[n];
    float acc = 0.f;
    for (int i = 0; i < deg; ++i) {
        int c = payr[st + i];
        acc += femb[(size_t)c * HDIM + h];
    }
    out[(size_t)n * HDIM + h] = acc * (1.0f / fmaxf((float)deg, 1.0f));
}

extern "C" void kernel_launch(void* const* d_in, const int* in_sizes, int n_in,
                              void* d_out, int out_size, void* d_ws, size_t ws_size,
                              hipStream_t stream) {
    const float* x         = (const float*)d_in[0];
    const float* fragments = (const float*)d_in[1];
    const float* emb_table = (const float*)d_in[2];
    const float* W_f       = (const float*)d_in[3];
    const float* b_f       = (const float*)d_in[4];
    const float* W_s       = (const float*)d_in[5];
    const float* b_s       = (const float*)d_in[6];
    const int*   row       = (const int*)d_in[7];
    const int*   col       = (const int*)d_in[8];
    float* out = (float*)d_out;

    const int N = 200000, F = 50000, E = 400000;
    const int NBC = (F + 255) / 256;   // 196
    const int NBR = (N + 255) / 256;   // 782

    float* femb   = (float*)d_ws;                  // F*128
    int* cntc     = (int*)(femb + (size_t)F * HDIM); // F
    int* cntr     = cntc + F;                      // N
    int* curc     = cntr + N;                      // F
    int* curr     = curc + F;                      // N
    int* basec    = curr + N;                      // F
    int* baser    = basec + F;                     // N
    int* bsc      = baser + N;                     // 1024
    int* bsr      = bsc + 1024;                    // 1024
    int* payc     = bsr + 1024;                    // E
    int* payr     = payc + E;                      // E
    int* frag_id  = payr + E;                      // F
    float* Wfs    = (float*)(frag_id + F);         // 128*128
    float* E2     = Wfs + HDIM * HDIM;             // VOCAB*128
    float* bfs    = E2 + VOCAB * HDIM;             // 128

    // zero cntc,cntr,curc,curr (contiguous: F+N+F+N ints)
    hipMemsetAsync(cntc, 0, (size_t)(2 * (F + N)) * sizeof(int), stream);

    k_prep_w<<<HDIM + 1, HDIM, 0, stream>>>(W_f, b_f, W_s, b_s, Wfs, bfs);
    k_E2<<<VOCAB, HDIM, 0, stream>>>(emb_table, Wfs, E2);
    k_argmax<<<(F + 3) / 4, 256, 0, stream>>>(fragments, frag_id, F);

    k_count<<<(E + 255) / 256, 256, 0, stream>>>(row, col, cntr, cntc, E);
    k_blocksum<<<NBC, 256, 0, stream>>>(cntc, F, bsc);
    k_blocksum<<<NBR, 256, 0, stream>>>(cntr, N, bsr);
    k_scan_bsum<<<1, 1024, 0, stream>>>(bsc, NBC);
    k_scan_bsum<<<1, 1024, 0, stream>>>(bsr, NBR);
    k_base<<<NBC, 256, 0, stream>>>(cntc, bsc, F, basec);
    k_base<<<NBR, 256, 0, stream>>>(cntr, bsr, N, baser);
    k_place<<<(E + 255) / 256, 256, 0, stream>>>(row, col, basec, baser, curc, curr,
                                                 payc, payr, E);

    k_frag<<<F / FB, HDIM, 0, stream>>>(x, basec, cntc, payc, frag_id, W_s, E2, bfs, femb);
    k_node<<<(N + 1) / 2, 256, 0, stream>>>(femb, baser, cntr, payr, out, N);
}

// Round 3
// 265.678 us; speedup vs baseline: 2.1175x; 1.5853x over previous
//
#include <hip/hip_runtime.h>

#define HDIM 128
#define VOCAB 800
#define FB 16

// ---------- fold W_f into W_s bottom half: Wfs = W_f @ W_s[128:], bfs = b_f @ W_s[128:] + b_s
__global__ void k_prep_w(const float* __restrict__ W_f, const float* __restrict__ b_f,
                         const float* __restrict__ W_s, const float* __restrict__ b_s,
                         float* __restrict__ Wfs, float* __restrict__ bfs) {
    int j = threadIdx.x;
    int i = blockIdx.x;
    if (i < HDIM) {
        float acc = 0.f;
        for (int k = 0; k < HDIM; ++k)
            acc = fmaf(W_f[i * HDIM + k], W_s[(HDIM + k) * HDIM + j], acc);
        Wfs[i * HDIM + j] = acc;
    } else {
        float acc = b_s[j];
        for (int k = 0; k < HDIM; ++k)
            acc = fmaf(b_f[k], W_s[(HDIM + k) * HDIM + j], acc);
        bfs[j] = acc;
    }
}

// ---------- E2 = emb_table @ Wfs   [VOCAB,128]
__global__ void k_E2(const float* __restrict__ emb, const float* __restrict__ Wfs,
                     float* __restrict__ E2) {
    int j = threadIdx.x, v = blockIdx.x;
    float acc = 0.f;
    for (int k = 0; k < HDIM; ++k)
        acc = fmaf(emb[v * HDIM + k], Wfs[k * HDIM + j], acc);
    E2[v * HDIM + j] = acc;
}

// ---------- frag_id = argmax(fragments, axis=1), first occurrence (float4)
__global__ void k_argmax(const float* __restrict__ frags, int* __restrict__ frag_id, int F) {
    int wave = (int)((blockIdx.x * (long long)blockDim.x + threadIdx.x) >> 6);
    int lane = threadIdx.x & 63;
    if (wave >= F) return;
    const float4* r = reinterpret_cast<const float4*>(frags + (size_t)wave * VOCAB); // 200 f4
    float best = -1e30f;
    int bidx = 0;
    for (int i = lane; i < VOCAB / 4; i += 64) {
        float4 v = r[i];
        int b = i * 4;
        if (v.x > best) { best = v.x; bidx = b + 0; }
        if (v.y > best) { best = v.y; bidx = b + 1; }
        if (v.z > best) { best = v.z; bidx = b + 2; }
        if (v.w > best) { best = v.w; bidx = b + 3; }   // per-lane idx increasing -> first kept
    }
    for (int off = 32; off > 0; off >>= 1) {
        float ov = __shfl_xor(best, off, 64);
        int   oi = __shfl_xor(bidx, off, 64);
        if (ov > best || (ov == best && oi < bidx)) { best = ov; bidx = oi; }
    }
    if (lane == 0) frag_id[wave] = bidx;
}

// ---------- CSR build: counts
__global__ void k_count(const int* __restrict__ row, const int* __restrict__ col,
                        int* __restrict__ cntr, int* __restrict__ cntc, int E) {
    int e = blockIdx.x * 256 + threadIdx.x;
    if (e >= E) return;
    atomicAdd(&cntr[row[e]], 1);
    atomicAdd(&cntc[col[e]], 1);
}

// ---------- per-256-block sums
__global__ void k_blocksum(const int* __restrict__ cnt, int L, int* __restrict__ bsum) {
    __shared__ int s[256];
    int t = threadIdx.x;
    int i = blockIdx.x * 256 + t;
    s[t] = (i < L) ? cnt[i] : 0;
    __syncthreads();
    for (int o = 128; o > 0; o >>= 1) {
        if (t < o) s[t] += s[t + o];
        __syncthreads();
    }
    if (t == 0) bsum[blockIdx.x] = s[0];
}

// ---------- exclusive scan of block sums (nb <= 1024), single block
__global__ void k_scan_bsum(int* __restrict__ bsum, int nb) {
    __shared__ int s[1024];
    int t = threadIdx.x;
    int v = (t < nb) ? bsum[t] : 0;
    s[t] = v;
    __syncthreads();
    for (int o = 1; o < 1024; o <<= 1) {
        int a = (t >= o) ? s[t - o] : 0;
        __syncthreads();
        s[t] += a;
        __syncthreads();
    }
    if (t < nb) bsum[t] = s[t] - v;  // exclusive
}

// ---------- base[i] = bsum[block] + exclusive scan within block
__global__ void k_base(const int* __restrict__ cnt, const int* __restrict__ bsum, int L,
                       int* __restrict__ base) {
    __shared__ int s[256];
    int t = threadIdx.x;
    int i = blockIdx.x * 256 + t;
    int v = (i < L) ? cnt[i] : 0;
    s[t] = v;
    __syncthreads();
    for (int o = 1; o < 256; o <<= 1) {
        int a = (t >= o) ? s[t - o] : 0;
        __syncthreads();
        s[t] += a;
        __syncthreads();
    }
    if (i < L) base[i] = bsum[blockIdx.x] + s[t] - v;
}

// ---------- place edges into both CSRs (payload = the opposite endpoint)
__global__ void k_place(const int* __restrict__ row, const int* __restrict__ col,
                        const int* __restrict__ basec, const int* __restrict__ baser,
                        int* __restrict__ curc, int* __restrict__ curr,
                        int* __restrict__ payc, int* __restrict__ payr, int E) {
    int e = blockIdx.x * 256 + threadIdx.x;
    if (e >= E) return;
    int r = row[e], c = col[e];
    int pc = atomicAdd(&curc[c], 1);
    payc[basec[c] + pc] = r;
    int pr = atomicAdd(&curr[r], 1);
    payr[baser[r] + pr] = c;
}

// ---------- fragment pool + femb fused, high-MLP version:
// 256 thr = 8 groups of 32 lanes; each group owns 2 fragments; float4 row loads;
// edge indices prefetched 32-wide and broadcast via shfl; 4 independent accumulators.
__global__ __launch_bounds__(256) void k_frag(
        const float* __restrict__ x, const int* __restrict__ basec,
        const int* __restrict__ cntc, const int* __restrict__ payc,
        const int* __restrict__ frag_id, const float* __restrict__ W_s,
        const float* __restrict__ E2, const float* __restrict__ bfs,
        float* __restrict__ femb) {
    __shared__ float s[FB][HDIM];
    int t = threadIdx.x;
    int g = t >> 5, l = t & 31;
    int fb = blockIdx.x * FB;
#pragma unroll
    for (int rep = 0; rep < FB / 8; ++rep) {
        int f = rep * 8 + g;
        int fi = fb + f;
        int st = basec[fi], deg = cntc[fi];
        float4 a0 = make_float4(0.f, 0.f, 0.f, 0.f);
        float4 a1 = a0, a2 = a0, a3 = a0;
        for (int i = 0; i < deg; i += 32) {
            int nb = min(deg - i, 32);
            int idx = (l < nb) ? payc[st + i + l] : 0;  // one coalesced 32-wide load
            int j = 0;
            for (; j + 4 <= nb; j += 4) {
                int r0 = __shfl(idx, j + 0, 32);
                int r1 = __shfl(idx, j + 1, 32);
                int r2 = __shfl(idx, j + 2, 32);
                int r3 = __shfl(idx, j + 3, 32);
                float4 v0 = *reinterpret_cast<const float4*>(x + (size_t)r0 * HDIM + l * 4);
                float4 v1 = *reinterpret_cast<const float4*>(x + (size_t)r1 * HDIM + l * 4);
                float4 v2 = *reinterpret_cast<const float4*>(x + (size_t)r2 * HDIM + l * 4);
                float4 v3 = *reinterpret_cast<const float4*>(x + (size_t)r3 * HDIM + l * 4);
                a0.x += v0.x; a0.y += v0.y; a0.z += v0.z; a0.w += v0.w;
                a1.x += v1.x; a1.y += v1.y; a1.z += v1.z; a1.w += v1.w;
                a2.x += v2.x; a2.y += v2.y; a2.z += v2.z; a2.w += v2.w;
                a3.x += v3.x; a3.y += v3.y; a3.z += v3.z; a3.w += v3.w;
            }
            for (; j < nb; ++j) {
                int r = __shfl(idx, j, 32);
                float4 v = *reinterpret_cast<const float4*>(x + (size_t)r * HDIM + l * 4);
                a0.x += v.x; a0.y += v.y; a0.z += v.z; a0.w += v.w;
            }
        }
        float inv = 1.0f / fmaxf((float)deg, 1.0f);
        float4 a;
        a.x = (a0.x + a1.x + a2.x + a3.x) * inv;
        a.y = (a0.y + a1.y + a2.y + a3.y) * inv;
        a.z = (a0.z + a1.z + a2.z + a3.z) * inv;
        a.w = (a0.w + a1.w + a2.w + a3.w) * inv;
        *reinterpret_cast<float4*>(&s[f][l * 4]) = a;
    }
    __syncthreads();
    // matvec: thread handles dim d, 8 fragments (half-block split)
    int d = t & 127;
    int fh = t >> 7;  // 0..1
    float bv = bfs[d];
    float acc[8];
#pragma unroll
    for (int f = 0; f < 8; ++f)
        acc[f] = E2[(size_t)frag_id[fb + fh * 8 + f] * HDIM + d] + bv;
    for (int k = 0; k < HDIM; k += 4) {
        float w0 = W_s[(k + 0) * HDIM + d];
        float w1 = W_s[(k + 1) * HDIM + d];
        float w2 = W_s[(k + 2) * HDIM + d];
        float w3 = W_s[(k + 3) * HDIM + d];
#pragma unroll
        for (int f = 0; f < 8; ++f) {
            const float4 sv = *reinterpret_cast<const float4*>(&s[fh * 8 + f][k]);
            acc[f] = fmaf(sv.x, w0, acc[f]);
            acc[f] = fmaf(sv.y, w1, acc[f]);
            acc[f] = fmaf(sv.z, w2, acc[f]);
            acc[f] = fmaf(sv.w, w3, acc[f]);
        }
    }
#pragma unroll
    for (int f = 0; f < 8; ++f)
        femb[(size_t)(fb + fh * 8 + f) * HDIM + d] = acc[f];
}

// ---------- node pool + divide fused, high-MLP version (8 nodes/block, float4)
__global__ __launch_bounds__(256) void k_node(
        const float* __restrict__ femb, const int* __restrict__ baser,
        const int* __restrict__ cntr, const int* __restrict__ payr,
        float* __restrict__ out, int N) {
    int t = threadIdx.x;
    int g = t >> 5, l = t & 31;
    int n = blockIdx.x * 8 + g;
    if (n >= N) return;
    int st = baser[n], deg = cntr[n];
    float4 a0 = make_float4(0.f, 0.f, 0.f, 0.f);
    float4 a1 = a0, a2 = a0, a3 = a0;
    for (int i = 0; i < deg; i += 32) {
        int nb = min(deg - i, 32);
        int idx = (l < nb) ? payr[st + i + l] : 0;
        int j = 0;
        for (; j + 4 <= nb; j += 4) {
            int c0 = __shfl(idx, j + 0, 32);
            int c1 = __shfl(idx, j + 1, 32);
            int c2 = __shfl(idx, j + 2, 32);
            int c3 = __shfl(idx, j + 3, 32);
            float4 v0 = *reinterpret_cast<const float4*>(femb + (size_t)c0 * HDIM + l * 4);
            float4 v1 = *reinterpret_cast<const float4*>(femb + (size_t)c1 * HDIM + l * 4);
            float4 v2 = *reinterpret_cast<const float4*>(femb + (size_t)c2 * HDIM + l * 4);
            float4 v3 = *reinterpret_cast<const float4*>(femb + (size_t)c3 * HDIM + l * 4);
            a0.x += v0.x; a0.y += v0.y; a0.z += v0.z; a0.w += v0.w;
            a1.x += v1.x; a1.y += v1.y; a1.z += v1.z; a1.w += v1.w;
            a2.x += v2.x; a2.y += v2.y; a2.z += v2.z; a2.w += v2.w;
            a3.x += v3.x; a3.y += v3.y; a3.z += v3.z; a3.w += v3.w;
        }
        for (; j < nb; ++j) {
            int c = __shfl(idx, j, 32);
            float4 v = *reinterpret_cast<const float4*>(femb + (size_t)c * HDIM + l * 4);
            a0.x += v.x; a0.y += v.y; a0.z += v.z; a0.w += v.w;
        }
    }
    float inv = 1.0f / fmaxf((float)deg, 1.0f);
    float4 a;
    a.x = (a0.x + a1.x + a2.x + a3.x) * inv;
    a.y = (a0.y + a1.y + a2.y + a3.y) * inv;
    a.z = (a0.z + a1.z + a2.z + a3.z) * inv;
    a.w = (a0.w + a1.w + a2.w + a3.w) * inv;
    *reinterpret_cast<float4*>(out + (size_t)n * HDIM + l * 4) = a;
}

extern "C" void kernel_launch(void* const* d_in, const int* in_sizes, int n_in,
                              void* d_out, int out_size, void* d_ws, size_t ws_size,
                              hipStream_t stream) {
    const float* x         = (const float*)d_in[0];
    const float* fragments = (const float*)d_in[1];
    const float* emb_table = (const float*)d_in[2];
    const float* W_f       = (const float*)d_in[3];
    const float* b_f       = (const float*)d_in[4];
    const float* W_s       = (const float*)d_in[5];
    const float* b_s       = (const float*)d_in[6];
    const int*   row       = (const int*)d_in[7];
    const int*   col       = (const int*)d_in[8];
    float* out = (float*)d_out;

    const int N = 200000, F = 50000, E = 400000;
    const int NBC = (F + 255) / 256;   // 196
    const int NBR = (N + 255) / 256;   // 782

    float* femb   = (float*)d_ws;                    // F*128
    int* cntc     = (int*)(femb + (size_t)F * HDIM); // F
    int* cntr     = cntc + F;                        // N
    int* curc     = cntr + N;                        // F
    int* curr     = curc + F;                        // N
    int* basec    = curr + N;                        // F
    int* baser    = basec + F;                       // N
    int* bsc      = baser + N;                       // 1024
    int* bsr      = bsc + 1024;                      // 1024
    int* payc     = bsr + 1024;                      // E
    int* payr     = payc + E;                        // E
    int* frag_id  = payr + E;                        // F
    float* Wfs    = (float*)(frag_id + F);           // 128*128
    float* E2     = Wfs + HDIM * HDIM;               // VOCAB*128
    float* bfs    = E2 + VOCAB * HDIM;               // 128

    // zero cntc,cntr,curc,curr (contiguous: F+N+F+N ints)
    hipMemsetAsync(cntc, 0, (size_t)(2 * (F + N)) * sizeof(int), stream);

    k_prep_w<<<HDIM + 1, HDIM, 0, stream>>>(W_f, b_f, W_s, b_s, Wfs, bfs);
    k_E2<<<VOCAB, HDIM, 0, stream>>>(emb_table, Wfs, E2);
    k_argmax<<<(F + 3) / 4, 256, 0, stream>>>(fragments, frag_id, F);

    k_count<<<(E + 255) / 256, 256, 0, stream>>>(row, col, cntr, cntc, E);
    k_blocksum<<<NBC, 256, 0, stream>>>(cntc, F, bsc);
    k_blocksum<<<NBR, 256, 0, stream>>>(cntr, N, bsr);
    k_scan_bsum<<<1, 1024, 0, stream>>>(bsc, NBC);
    k_scan_bsum<<<1, 1024, 0, stream>>>(bsr, NBR);
    k_base<<<NBC, 256, 0, stream>>>(cntc, bsc, F, basec);
    k_base<<<NBR, 256, 0, stream>>>(cntr, bsr, N, baser);
    k_place<<<(E + 255) / 256, 256, 0, stream>>>(row, col, basec, baser, curc, curr,
                                                 payc, payr, E);

    k_frag<<<F / FB, 256, 0, stream>>>(x, basec, cntc, payc, frag_id, W_s, E2, bfs, femb);
    k_node<<<(N + 7) / 8, 256, 0, stream>>>(femb, baser, cntr, payr, out, N);
}

// Round 4
// 265.524 us; speedup vs baseline: 2.1187x; 1.0006x over previous
//
#include <hip/hip_runtime.h>

#define HDIM 128
#define VOCAB 800
#define FB 16
#define TILE 1024

#define ACC4(a, v) { a.x += v.x; a.y += v.y; a.z += v.z; a.w += v.w; }

// ---------- fused: E2 = (emb @ W_f) @ W_s_bot  (blocks 0..799), bfs = b_f @ W_s_bot + b_s (block 800)
__global__ void k_prep(const float* __restrict__ emb, const float* __restrict__ W_f,
                       const float* __restrict__ W_s, const float* __restrict__ b_f,
                       const float* __restrict__ b_s, float* __restrict__ E2,
                       float* __restrict__ bfs) {
    __shared__ float e[HDIM], t1[HDIM];
    int j = threadIdx.x;
    int v = blockIdx.x;
    if (v < VOCAB) {
        e[j] = emb[(size_t)v * HDIM + j];
        __syncthreads();
        float a = 0.f;
        for (int k = 0; k < HDIM; ++k)
            a = fmaf(e[k], W_f[k * HDIM + j], a);
        t1[j] = a;
        __syncthreads();
        float b = 0.f;
        for (int k = 0; k < HDIM; ++k)
            b = fmaf(t1[k], W_s[(HDIM + k) * HDIM + j], b);
        E2[(size_t)v * HDIM + j] = b;
    } else {
        e[j] = b_f[j];
        __syncthreads();
        float b = b_s[j];
        for (int k = 0; k < HDIM; ++k)
            b = fmaf(e[k], W_s[(HDIM + k) * HDIM + j], b);
        bfs[j] = b;
    }
}

// ---------- fused: argmax(fragments) [blocks 0..12499] + edge count [blocks 12500..12890]
__global__ void k_amc(const float* __restrict__ frags, int* __restrict__ frag_id,
                      const int* __restrict__ row, const int* __restrict__ col,
                      int* __restrict__ cntr, int* __restrict__ cntc) {
    int b = blockIdx.x;
    if (b < 12500) {
        int wave = b * 4 + (threadIdx.x >> 6);
        int lane = threadIdx.x & 63;
        const float4* r = reinterpret_cast<const float4*>(frags + (size_t)wave * VOCAB);
        float best = -1e30f;
        int bidx = 0;
        for (int i = lane; i < VOCAB / 4; i += 64) {
            float4 v = r[i];
            int base = i * 4;
            if (v.x > best) { best = v.x; bidx = base + 0; }
            if (v.y > best) { best = v.y; bidx = base + 1; }
            if (v.z > best) { best = v.z; bidx = base + 2; }
            if (v.w > best) { best = v.w; bidx = base + 3; }
        }
        for (int off = 32; off > 0; off >>= 1) {
            float ov = __shfl_xor(best, off, 64);
            int   oi = __shfl_xor(bidx, off, 64);
            if (ov > best || (ov == best && oi < bidx)) { best = ov; bidx = oi; }
        }
        if (lane == 0) frag_id[wave] = bidx;
    } else {
        int i = (b - 12500) * 256 + threadIdx.x;  // over E/4 = 100000 int4s
        if (i < 100000) {
            int4 r4 = reinterpret_cast<const int4*>(row)[i];
            int4 c4 = reinterpret_cast<const int4*>(col)[i];
            atomicAdd(&cntr[r4.x], 1); atomicAdd(&cntr[r4.y], 1);
            atomicAdd(&cntr[r4.z], 1); atomicAdd(&cntr[r4.w], 1);
            atomicAdd(&cntc[c4.x], 1); atomicAdd(&cntc[c4.y], 1);
            atomicAdd(&cntc[c4.z], 1); atomicAdd(&cntc[c4.w], 1);
        }
    }
}

// ---------- per-256-block sums, col then row (fused)
__global__ void k_bsum2(const int* __restrict__ cntc, const int* __restrict__ cntr,
                        int* __restrict__ bsc, int* __restrict__ bsr, int NBC, int F, int N) {
    __shared__ int s[256];
    int t = threadIdx.x;
    const int* cnt;
    int* bsum;
    int bb, L;
    if ((int)blockIdx.x < NBC) { cnt = cntc; bsum = bsc; bb = blockIdx.x; L = F; }
    else                       { cnt = cntr; bsum = bsr; bb = blockIdx.x - NBC; L = N; }
    int i = bb * 256 + t;
    s[t] = (i < L) ? cnt[i] : 0;
    __syncthreads();
    for (int o = 128; o > 0; o >>= 1) {
        if (t < o) s[t] += s[t + o];
        __syncthreads();
    }
    if (t == 0) bsum[bb] = s[0];
}

// ---------- exclusive scan of both block-sum arrays (2 blocks)
__global__ void k_scan2(int* __restrict__ bsc, int* __restrict__ bsr, int nbc, int nbr) {
    __shared__ int s[1024];
    int* bsum = (blockIdx.x == 0) ? bsc : bsr;
    int nb    = (blockIdx.x == 0) ? nbc : nbr;
    int t = threadIdx.x;
    int v = (t < nb) ? bsum[t] : 0;
    s[t] = v;
    __syncthreads();
    for (int o = 1; o < 1024; o <<= 1) {
        int a = (t >= o) ? s[t - o] : 0;
        __syncthreads();
        s[t] += a;
        __syncthreads();
    }
    if (t < nb) bsum[t] = s[t] - v;
}

// ---------- base[i] = bsum[block] + in-block exclusive scan (col + row fused)
__global__ void k_base2(const int* __restrict__ cntc, const int* __restrict__ cntr,
                        const int* __restrict__ bsc, const int* __restrict__ bsr,
                        int* __restrict__ basec, int* __restrict__ baser,
                        int NBC, int F, int N) {
    __shared__ int s[256];
    int t = threadIdx.x;
    const int *cnt, *bsum;
    int* base;
    int bb, L;
    if ((int)blockIdx.x < NBC) { cnt = cntc; bsum = bsc; base = basec; bb = blockIdx.x; L = F; }
    else                       { cnt = cntr; bsum = bsr; base = baser; bb = blockIdx.x - NBC; L = N; }
    int i = bb * 256 + t;
    int v = (i < L) ? cnt[i] : 0;
    s[t] = v;
    __syncthreads();
    for (int o = 1; o < 256; o <<= 1) {
        int a = (t >= o) ? s[t - o] : 0;
        __syncthreads();
        s[t] += a;
        __syncthreads();
    }
    if (i < L) base[i] = bsum[bb] + s[t] - v;
}

// ---------- place edges into both CSRs (payload = opposite endpoint)
__global__ void k_place(const int* __restrict__ row, const int* __restrict__ col,
                        const int* __restrict__ basec, const int* __restrict__ baser,
                        int* __restrict__ curc, int* __restrict__ curr,
                        int* __restrict__ payc, int* __restrict__ payr, int E) {
    int e = blockIdx.x * 256 + threadIdx.x;
    if (e >= E) return;
    int r = row[e], c = col[e];
    int pc = atomicAdd(&curc[c], 1);
    payc[basec[c] + pc] = r;
    int pr = atomicAdd(&curr[r], 1);
    payr[baser[r] + pr] = c;
}

// ---------- fragment pool + femb fused; LDS idx staging, 2 frags x 2-deep chains per group
__global__ __launch_bounds__(256) void k_frag(
        const float* __restrict__ x, const int* __restrict__ basec,
        const int* __restrict__ cntc, const int* __restrict__ payc,
        const int* __restrict__ frag_id, const float* __restrict__ W_s,
        const float* __restrict__ E2, const float* __restrict__ bfs,
        float* __restrict__ femb) {
    __shared__ float s[FB][HDIM];
    __shared__ int eidx[TILE];
    int t = threadIdx.x;
    int g = t >> 5, l = t & 31;
    int fb = blockIdx.x * FB;
    int fi0 = fb + g, fi1 = fb + 8 + g;
    int st0 = basec[fi0], d0 = cntc[fi0];
    int st1 = basec[fi1], d1 = cntc[fi1];
    int p0 = basec[fb];
    int pend = basec[fb + FB - 1] + cntc[fb + FB - 1];
    const float4* x4 = reinterpret_cast<const float4*>(x);
    float4 a0A = make_float4(0.f, 0.f, 0.f, 0.f), a0B = a0A, a1A = a0A, a1B = a0A;
    for (int tb = p0; tb < pend; tb += TILE) {
        int nload = min(TILE, pend - tb);
        for (int i = t; i < nload; i += 256) eidx[i] = payc[tb + i];
        __syncthreads();
        int lim = tb + nload;
        int lo0 = max(st0, tb) - tb, hi0 = min(st0 + d0, lim) - tb;
        int lo1 = max(st1, tb) - tb, hi1 = min(st1 + d1, lim) - tb;
        int m = max(hi0 - lo0, hi1 - lo1);
        for (int j = 0; j < m; j += 2) {
            if (lo0 + j < hi0)     { float4 v = x4[(size_t)eidx[lo0 + j]     * 32 + l]; ACC4(a0A, v); }
            if (lo0 + j + 1 < hi0) { float4 v = x4[(size_t)eidx[lo0 + j + 1] * 32 + l]; ACC4(a0B, v); }
            if (lo1 + j < hi1)     { float4 v = x4[(size_t)eidx[lo1 + j]     * 32 + l]; ACC4(a1A, v); }
            if (lo1 + j + 1 < hi1) { float4 v = x4[(size_t)eidx[lo1 + j + 1] * 32 + l]; ACC4(a1B, v); }
        }
        __syncthreads();
    }
    float inv0 = 1.0f / fmaxf((float)d0, 1.0f);
    float inv1 = 1.0f / fmaxf((float)d1, 1.0f);
    float4 r0, r1;
    r0.x = (a0A.x + a0B.x) * inv0; r0.y = (a0A.y + a0B.y) * inv0;
    r0.z = (a0A.z + a0B.z) * inv0; r0.w = (a0A.w + a0B.w) * inv0;
    r1.x = (a1A.x + a1B.x) * inv1; r1.y = (a1A.y + a1B.y) * inv1;
    r1.z = (a1A.z + a1B.z) * inv1; r1.w = (a1A.w + a1B.w) * inv1;
    *reinterpret_cast<float4*>(&s[g][l * 4]) = r0;
    *reinterpret_cast<float4*>(&s[8 + g][l * 4]) = r1;
    __syncthreads();
    // matvec: thread handles dim d for 8 fragments (half-block split)
    int d = t & 127;
    int fh = t >> 7;  // 0..1
    float bv = bfs[d];
    float acc[8];
#pragma unroll
    for (int f = 0; f < 8; ++f)
        acc[f] = E2[(size_t)frag_id[fb + fh * 8 + f] * HDIM + d] + bv;
    for (int k = 0; k < HDIM; k += 4) {
        float w0 = W_s[(k + 0) * HDIM + d];
        float w1 = W_s[(k + 1) * HDIM + d];
        float w2 = W_s[(k + 2) * HDIM + d];
        float w3 = W_s[(k + 3) * HDIM + d];
#pragma unroll
        for (int f = 0; f < 8; ++f) {
            const float4 sv = *reinterpret_cast<const float4*>(&s[fh * 8 + f][k]);
            acc[f] = fmaf(sv.x, w0, acc[f]);
            acc[f] = fmaf(sv.y, w1, acc[f]);
            acc[f] = fmaf(sv.z, w2, acc[f]);
            acc[f] = fmaf(sv.w, w3, acc[f]);
        }
    }
#pragma unroll
    for (int f = 0; f < 8; ++f)
        femb[(size_t)(fb + fh * 8 + f) * HDIM + d] = acc[f];
}

// ---------- node pool + divide fused; LDS idx staging, 4 nodes x 2-deep chains per group
__global__ __launch_bounds__(256) void k_node(
        const float* __restrict__ femb, const int* __restrict__ baser,
        const int* __restrict__ cntr, const int* __restrict__ payr,
        float* __restrict__ out, int N) {
    __shared__ int eidx[TILE];
    int t = threadIdx.x;
    int g = t >> 5, l = t & 31;
    int n0 = blockIdx.x * 32;
    int ng = n0 + g * 4;
    int p0 = baser[n0];
    int pend = baser[n0 + 31] + cntr[n0 + 31];
    int st0 = baser[ng + 0], d0 = cntr[ng + 0];
    int st1 = baser[ng + 1], d1 = cntr[ng + 1];
    int st2 = baser[ng + 2], d2 = cntr[ng + 2];
    int st3 = baser[ng + 3], d3 = cntr[ng + 3];
    const float4* f4 = reinterpret_cast<const float4*>(femb);
    float4 z = make_float4(0.f, 0.f, 0.f, 0.f);
    float4 a0A = z, a0B = z, a1A = z, a1B = z, a2A = z, a2B = z, a3A = z, a3B = z;
    for (int tb = p0; tb < pend; tb += TILE) {
        int nload = min(TILE, pend - tb);
        for (int i = t; i < nload; i += 256) eidx[i] = payr[tb + i];
        __syncthreads();
        int lim = tb + nload;
        int lo0 = max(st0, tb) - tb, hi0 = min(st0 + d0, lim) - tb;
        int lo1 = max(st1, tb) - tb, hi1 = min(st1 + d1, lim) - tb;
        int lo2 = max(st2, tb) - tb, hi2 = min(st2 + d2, lim) - tb;
        int lo3 = max(st3, tb) - tb, hi3 = min(st3 + d3, lim) - tb;
        int m = max(max(hi0 - lo0, hi1 - lo1), max(hi2 - lo2, hi3 - lo3));
        for (int j = 0; j < m; j += 2) {
            if (lo0 + j < hi0)     { float4 v = f4[(size_t)eidx[lo0 + j]     * 32 + l]; ACC4(a0A, v); }
            if (lo0 + j + 1 < hi0) { float4 v = f4[(size_t)eidx[lo0 + j + 1] * 32 + l]; ACC4(a0B, v); }
            if (lo1 + j < hi1)     { float4 v = f4[(size_t)eidx[lo1 + j]     * 32 + l]; ACC4(a1A, v); }
            if (lo1 + j + 1 < hi1) { float4 v = f4[(size_t)eidx[lo1 + j + 1] * 32 + l]; ACC4(a1B, v); }
            if (lo2 + j < hi2)     { float4 v = f4[(size_t)eidx[lo2 + j]     * 32 + l]; ACC4(a2A, v); }
            if (lo2 + j + 1 < hi2) { float4 v = f4[(size_t)eidx[lo2 + j + 1] * 32 + l]; ACC4(a2B, v); }
            if (lo3 + j < hi3)     { float4 v = f4[(size_t)eidx[lo3 + j]     * 32 + l]; ACC4(a3A, v); }
            if (lo3 + j + 1 < hi3) { float4 v = f4[(size_t)eidx[lo3 + j + 1] * 32 + l]; ACC4(a3B, v); }
        }
        __syncthreads();
    }
    float4* o4 = reinterpret_cast<float4*>(out);
    float4 r;
    float inv;
    inv = 1.0f / fmaxf((float)d0, 1.0f);
    r.x = (a0A.x + a0B.x) * inv; r.y = (a0A.y + a0B.y) * inv;
    r.z = (a0A.z + a0B.z) * inv; r.w = (a0A.w + a0B.w) * inv;
    o4[(size_t)(ng + 0) * 32 + l] = r;
    inv = 1.0f / fmaxf((float)d1, 1.0f);
    r.x = (a1A.x + a1B.x) * inv; r.y = (a1A.y + a1B.y) * inv;
    r.z = (a1A.z + a1B.z) * inv; r.w = (a1A.w + a1B.w) * inv;
    o4[(size_t)(ng + 1) * 32 + l] = r;
    inv = 1.0f / fmaxf((float)d2, 1.0f);
    r.x = (a2A.x + a2B.x) * inv; r.y = (a2A.y + a2B.y) * inv;
    r.z = (a2A.z + a2B.z) * inv; r.w = (a2A.w + a2B.w) * inv;
    o4[(size_t)(ng + 2) * 32 + l] = r;
    inv = 1.0f / fmaxf((float)d3, 1.0f);
    r.x = (a3A.x + a3B.x) * inv; r.y = (a3A.y + a3B.y) * inv;
    r.z = (a3A.z + a3B.z) * inv; r.w = (a3A.w + a3B.w) * inv;
    o4[(size_t)(ng + 3) * 32 + l] = r;
}

extern "C" void kernel_launch(void* const* d_in, const int* in_sizes, int n_in,
                              void* d_out, int out_size, void* d_ws, size_t ws_size,
                              hipStream_t stream) {
    const float* x         = (const float*)d_in[0];
    const float* fragments = (const float*)d_in[1];
    const float* emb_table = (const float*)d_in[2];
    const float* W_f       = (const float*)d_in[3];
    const float* b_f       = (const float*)d_in[4];
    const float* W_s       = (const float*)d_in[5];
    const float* b_s       = (const float*)d_in[6];
    const int*   row       = (const int*)d_in[7];
    const int*   col       = (const int*)d_in[8];
    float* out = (float*)d_out;

    const int N = 200000, F = 50000, E = 400000;
    const int NBC = (F + 255) / 256;   // 196
    const int NBR = (N + 255) / 256;   // 782

    float* femb   = (float*)d_ws;                    // F*128
    int* cntc     = (int*)(femb + (size_t)F * HDIM); // F
    int* cntr     = cntc + F;                        // N
    int* curc     = cntr + N;                        // F
    int* curr     = curc + F;                        // N
    int* basec    = curr + N;                        // F
    int* baser    = basec + F;                       // N
    int* bsc      = baser + N;                       // 1024
    int* bsr      = bsc + 1024;                      // 1024
    int* payc     = bsr + 1024;                      // E
    int* payr     = payc + E;                        // E
    int* frag_id  = payr + E;                        // F
    float* E2     = (float*)(frag_id + F);           // VOCAB*128
    float* bfs    = E2 + VOCAB * HDIM;               // 128

    // zero cntc,cntr,curc,curr (contiguous: 2*(F+N) ints)
    hipMemsetAsync(cntc, 0, (size_t)(2 * (F + N)) * sizeof(int), stream);

    k_prep<<<VOCAB + 1, HDIM, 0, stream>>>(emb_table, W_f, W_s, b_f, b_s, E2, bfs);
    k_amc<<<12500 + 391, 256, 0, stream>>>(fragments, frag_id, row, col, cntr, cntc);
    k_bsum2<<<NBC + NBR, 256, 0, stream>>>(cntc, cntr, bsc, bsr, NBC, F, N);
    k_scan2<<<2, 1024, 0, stream>>>(bsc, bsr, NBC, NBR);
    k_base2<<<NBC + NBR, 256, 0, stream>>>(cntc, cntr, bsc, bsr, basec, baser, NBC, F, N);
    k_place<<<(E + 255) / 256, 256, 0, stream>>>(row, col, basec, baser, curc, curr,
                                                 payc, payr, E);
    k_frag<<<F / FB, 256, 0, stream>>>(x, basec, cntc, payc, frag_id, W_s, E2, bfs, femb);
    k_node<<<N / 32, 256, 0, stream>>>(femb, baser, cntr, payr, out, N);
}